// Round 11
// baseline (171.230 us; speedup 1.0000x reference)
//
#include <hip/hip_runtime.h>
#include <hip/hip_bf16.h>

#define SEQ   2048
#define DM    1024
#define NH    16
#define DH    64
#define MAXD  128

typedef __attribute__((ext_vector_type(8))) short  short8;   // 8 bf16 = 4 VGPRs
typedef __attribute__((ext_vector_type(4))) float  float4v;  // MFMA 16x16 accumulator

__device__ __forceinline__ short8 ld8(const void* p) {
    short8 v; __builtin_memcpy(&v, p, 16); return v;
}
__device__ __forceinline__ void st8(void* p, short8 v) {
    __builtin_memcpy(p, &v, 16);
}
__device__ __forceinline__ short bf16bits(float f) {
    __hip_bfloat16 b = __float2bfloat16(f);
    short s; __builtin_memcpy(&s, &b, 2); return s;
}
// fast bf16 pack: round-half-up (2 VALU ops). Valid for finite f; used on P in [0,1].
__device__ __forceinline__ short bf16fast(float f) {
    unsigned u = __builtin_bit_cast(unsigned, f);
    return (short)((u + 0x8000u) >> 16);
}
__device__ __forceinline__ float bits2f(short s) {
    unsigned u = (unsigned)(unsigned short)s << 16;
    return __builtin_bit_cast(float, u);
}

// async global->LDS, 16 B per lane. lds = WAVE-UNIFORM base (HW adds lane*16).
__device__ __forceinline__ void async16(void* lds, const void* g) {
    __builtin_amdgcn_global_load_lds(
        (const __attribute__((address_space(1))) unsigned int*)g,
        (__attribute__((address_space(3))) unsigned int*)lds, 16, 0, 0);
}

// DPP cross-lane (16-lane group) reductions — VALU-latency, no LDS pipe.
template <int CTRL>
__device__ __forceinline__ float dppmov(float x) {
    return __builtin_bit_cast(float,
        __builtin_amdgcn_update_dpp(0, __builtin_bit_cast(int, x), CTRL, 0xf, 0xf, true));
}
__device__ __forceinline__ float red16max(float x) {
    x = fmaxf(x, dppmov<0xB1>(x));
    x = fmaxf(x, dppmov<0x4E>(x));
    x = fmaxf(x, dppmov<0x141>(x));
    x = fmaxf(x, dppmov<0x140>(x));
    return x;
}
__device__ __forceinline__ float red16sum(float x) {
    x += dppmov<0xB1>(x);
    x += dppmov<0x4E>(x);
    x += dppmov<0x141>(x);
    x += dppmov<0x140>(x);
    return x;
}

// ---------------------------------------------------------------------------
// Fused prep: weight transposes (fp32->bf16) + x fp32->bf16 convert.
// grid (160, 32): bx<96 wq-transpose; 96<=bx<128 wo-transpose; bx>=128 cvt.
// ---------------------------------------------------------------------------
__global__ __launch_bounds__(256) void prep_kernel(
    const float* __restrict__ wq, const float* __restrict__ wo,
    const float* __restrict__ x,
    __hip_bfloat16* __restrict__ wqT, __hip_bfloat16* __restrict__ woT,
    __hip_bfloat16* __restrict__ xb) {
    const int t = threadIdx.x;
    const int bx = blockIdx.x;
    if (bx >= 128) {
        const size_t id = (size_t)(bx - 128) * 32 + blockIdx.y;   // 0..1023
        const size_t i  = id * 2048 + t * 8;
        float f[8]; __builtin_memcpy(f, x + i, 32);
        short8 v;
#pragma unroll
        for (int j = 0; j < 8; ++j) v[j] = bf16bits(f[j]);
        st8(xb + i, v);
        return;
    }
    __shared__ __hip_bfloat16 tile[32][33];
    const int tx = t % 32, ty = t / 32;
    const int r0 = blockIdx.y * 32;
    const float* src; __hip_bfloat16* dst; int ss, ds, c0;
    if (bx < 96) { src = wq; dst = wqT; ss = 3 * DM; ds = DM; c0 = bx * 32; }
    else         { src = wo; dst = woT; ss = DM;     ds = DM; c0 = (bx - 96) * 32; }
#pragma unroll
    for (int i = 0; i < 4; ++i)
        tile[ty + i * 8][tx] = __float2bfloat16(src[(size_t)(r0 + ty + i * 8) * ss + c0 + tx]);
    __syncthreads();
#pragma unroll
    for (int i = 0; i < 4; ++i)
        dst[(size_t)(c0 + ty + i * 8) * ds + r0 + tx] = tile[tx][ty + i * 8];
}

// ---------------------------------------------------------------------------
// GEMM1: 128x64 tiles, BK=64 as two BK=32 planes (one barrier per 64 K).
// C[M][N] = A[M,K] * BT[N,K]^T, bf16 out. 768 blocks = 3/CU.
// ---------------------------------------------------------------------------
__global__ __launch_bounds__(256) void gemm_qkv(
    const __hip_bfloat16* __restrict__ A,
    const __hip_bfloat16* __restrict__ BT,
    __hip_bfloat16* __restrict__ C,
    int M, int N, int K) {
    __shared__ short As[2 * 128 * 32];   // [kc][m][32]
    __shared__ short Bs[2 * 64 * 32];    // [kc][n][32]

    const int t = threadIdx.x;
    const int w = t >> 6, lane = t & 63;
    const int l15 = lane & 15, quad = lane >> 4;
    const int row0 = blockIdx.y * 128;
    const int col0 = blockIdx.x * 64;
    const int wm = w >> 1, wn = w & 1;

    float4v acc[4][2];
#pragma unroll
    for (int i = 0; i < 4; ++i)
#pragma unroll
        for (int j = 0; j < 2; ++j) acc[i][j] = (float4v){0.f, 0.f, 0.f, 0.f};

    const int mloc0 = lane >> 2;
    const int u     = lane & 3;

    for (int k0 = 0; k0 < K; k0 += 64) {
#pragma unroll
        for (int kc = 0; kc < 2; ++kc) {
#pragma unroll
            for (int i = 0; i < 2; ++i) {
                const int c = 2 * w + i;   // A chunk 0..7
                async16(&As[kc * 4096 + c * 512],
                        A + (size_t)(row0 + c * 16 + mloc0) * K + k0 + kc * 32 + u * 8);
            }
            // B chunk = w (0..3)
            async16(&Bs[kc * 2048 + w * 512],
                    BT + (size_t)(col0 + w * 16 + mloc0) * K + k0 + kc * 32 + u * 8);
        }
        __syncthreads();

#pragma unroll
        for (int kc = 0; kc < 2; ++kc) {
            short8 af[4], bf[2];
#pragma unroll
            for (int mt = 0; mt < 4; ++mt)
                af[mt] = ld8(&As[kc * 4096 + (wm * 64 + mt * 16 + l15) * 32 + quad * 8]);
#pragma unroll
            for (int nt = 0; nt < 2; ++nt)
                bf[nt] = ld8(&Bs[kc * 2048 + (wn * 32 + nt * 16 + l15) * 32 + quad * 8]);
#pragma unroll
            for (int mt = 0; mt < 4; ++mt)
#pragma unroll
                for (int nt = 0; nt < 2; ++nt)
                    acc[mt][nt] = __builtin_amdgcn_mfma_f32_16x16x32_bf16(
                        af[mt], bf[nt], acc[mt][nt], 0, 0, 0);
        }
        __syncthreads();
    }

#pragma unroll
    for (int mt = 0; mt < 4; ++mt)
#pragma unroll
        for (int nt = 0; nt < 2; ++nt)
#pragma unroll
            for (int r = 0; r < 4; ++r) {
                const int row = row0 + wm * 64 + mt * 16 + quad * 4 + r;
                const int col = col0 + wn * 32 + nt * 16 + l15;
                C[(size_t)row * N + col] = __float2bfloat16(acc[mt][nt][r]);
            }
}

// ---------------------------------------------------------------------------
// GEMM3: 64x64 tiles, BK=64 as two BK=32 planes. fp32 out. 512 blocks = 2/CU.
// ---------------------------------------------------------------------------
__global__ __launch_bounds__(256) void gemm_out(
    const __hip_bfloat16* __restrict__ A,
    const __hip_bfloat16* __restrict__ BT,
    float* __restrict__ C,
    int M, int N, int K) {
    __shared__ short As[2 * 64 * 32];
    __shared__ short Bs[2 * 64 * 32];

    const int t = threadIdx.x;
    const int w = t >> 6, lane = t & 63;
    const int l15 = lane & 15, quad = lane >> 4;
    const int row0 = blockIdx.y * 64;
    const int col0 = blockIdx.x * 64;
    const int wm = w >> 1, wn = w & 1;

    float4v acc[2][2];
#pragma unroll
    for (int i = 0; i < 2; ++i)
#pragma unroll
        for (int j = 0; j < 2; ++j) acc[i][j] = (float4v){0.f, 0.f, 0.f, 0.f};

    const int mloc0 = lane >> 2;
    const int u     = lane & 3;

    for (int k0 = 0; k0 < K; k0 += 64) {
#pragma unroll
        for (int kc = 0; kc < 2; ++kc) {
            async16(&As[kc * 2048 + w * 512],
                    A + (size_t)(row0 + w * 16 + mloc0) * K + k0 + kc * 32 + u * 8);
            async16(&Bs[kc * 2048 + w * 512],
                    BT + (size_t)(col0 + w * 16 + mloc0) * K + k0 + kc * 32 + u * 8);
        }
        __syncthreads();

#pragma unroll
        for (int kc = 0; kc < 2; ++kc) {
            short8 af[2], bf[2];
#pragma unroll
            for (int mt = 0; mt < 2; ++mt)
                af[mt] = ld8(&As[kc * 2048 + (wm * 32 + mt * 16 + l15) * 32 + quad * 8]);
#pragma unroll
            for (int nt = 0; nt < 2; ++nt)
                bf[nt] = ld8(&Bs[kc * 2048 + (wn * 32 + nt * 16 + l15) * 32 + quad * 8]);
#pragma unroll
            for (int mt = 0; mt < 2; ++mt)
#pragma unroll
                for (int nt = 0; nt < 2; ++nt)
                    acc[mt][nt] = __builtin_amdgcn_mfma_f32_16x16x32_bf16(
                        af[mt], bf[nt], acc[mt][nt], 0, 0, 0);
        }
        __syncthreads();
    }

#pragma unroll
    for (int mt = 0; mt < 2; ++mt)
#pragma unroll
        for (int nt = 0; nt < 2; ++nt)
#pragma unroll
            for (int r = 0; r < 4; ++r) {
                const int row = row0 + wm * 32 + mt * 16 + quad * 4 + r;
                const int col = col0 + wn * 32 + nt * 16 + l15;
                C[(size_t)row * N + col] = acc[mt][nt][r];
            }
}

// ---------------------------------------------------------------------------
// MFMA flash attention, 128-key tiles, DPP softmax, uniform-bias fast path.
// V transposed in-LDS during staging (no global V^T needed).
// ---------------------------------------------------------------------------
#define TK  128   // keys per iteration
#define KS  68    // Kt row stride (shorts), 34 dwords
#define VS  132   // Vt / Pl row stride (shorts), 66 dwords

__global__ __launch_bounds__(256) void attn_mfma(
    const __hip_bfloat16* __restrict__ qkv,
    const float* __restrict__ rel_bias,
    __hip_bfloat16* __restrict__ attnb) {
    __shared__ short Kt[TK * KS];        // [key][d]
    __shared__ short Vt[DH * VS];        // [d][key]
    __shared__ short Pl[4 * 16 * VS];    // per-wave P [q][key]
    __shared__ float biasL[MAXD];

    const int t = threadIdx.x;
    const int w = t >> 6, lane = t & 63;
    const int l15 = lane & 15, quad = lane >> 4;
    const int h  = blockIdx.y;
    const int q0 = blockIdx.x * 64;
    const int qw = q0 + w * 16;

    if (t < MAXD) biasL[t] = rel_bias[t * NH + h];

    // persistent Q fragments, pre-scaled by 0.125 (exact in bf16)
    short8 qf[2];
#pragma unroll
    for (int c = 0; c < 2; ++c) {
        short8 raw = ld8(qkv + (size_t)(qw + l15) * (3 * DM) + h * DH + c * 32 + quad * 8);
#pragma unroll
        for (int j = 0; j < 8; ++j) qf[c][j] = bf16bits(bits2f(raw[j]) * 0.125f);
    }

    float4v o_acc[4];
#pragma unroll
    for (int nt = 0; nt < 4; ++nt) o_acc[nt] = (float4v){0.f, 0.f, 0.f, 0.f};
    float m_i[4], l_i[4];
#pragma unroll
    for (int r = 0; r < 4; ++r) { m_i[r] = -1e30f; l_i[r] = 0.f; }

    for (int kb = 0; kb < SEQ / TK; ++kb) {
        const int k0 = kb * TK;
        // stage K [key][d] (vector) and V transposed -> Vt[d][key] (scalar b16)
#pragma unroll
        for (int p = 0; p < 4; ++p) {
            const int idx = p * 256 + t;
            const int row = idx >> 3, u = idx & 7;
            st8(&Kt[row * KS + u * 8],
                ld8(qkv + (size_t)(k0 + row) * (3 * DM) + DM + h * DH + u * 8));
            short8 vv = ld8(qkv + (size_t)(k0 + row) * (3 * DM) + 2 * DM + h * DH + u * 8);
#pragma unroll
            for (int j = 0; j < 8; ++j)
                Vt[(u * 8 + j) * VS + row] = vv[j];
        }
        __syncthreads();

        // S = Q K^T : 8 key-blocks of 16
        float4v s_acc[8];
#pragma unroll
        for (int kt = 0; kt < 8; ++kt) s_acc[kt] = (float4v){0.f, 0.f, 0.f, 0.f};
#pragma unroll
        for (int c = 0; c < 2; ++c)
#pragma unroll
            for (int kt = 0; kt < 8; ++kt) {
                short8 kf = ld8(&Kt[(kt * 16 + l15) * KS + (c * 4 + quad) * 8]);
                s_acc[kt] = __builtin_amdgcn_mfma_f32_16x16x32_bf16(qf[c], kf, s_acc[kt], 0, 0, 0);
            }

        // bias (wave-uniform fast path when whole tile is at max distance)
        float sv[8][4];
        const int dlo = k0 - (qw + 15);
        const int dhi = qw - (k0 + TK - 1);
        if (dlo >= MAXD - 1 || dhi >= MAXD - 1) {
            const float bu = biasL[MAXD - 1];
#pragma unroll
            for (int kt = 0; kt < 8; ++kt)
#pragma unroll
                for (int r = 0; r < 4; ++r) sv[kt][r] = s_acc[kt][r] + bu;
        } else {
#pragma unroll
            for (int kt = 0; kt < 8; ++kt)
#pragma unroll
                for (int r = 0; r < 4; ++r) {
                    const int kg = k0 + kt * 16 + l15;
                    const int qg = qw + quad * 4 + r;
                    int rel = kg - qg; if (rel < 0) rel = -rel;
                    if (rel > MAXD - 1) rel = MAXD - 1;
                    sv[kt][r] = s_acc[kt][r] + biasL[rel];
                }
        }

        // online softmax (DPP reductions across the 16 lanes of each quad-row)
        float rowm[4];
#pragma unroll
        for (int r = 0; r < 4; ++r) {
            float m = sv[0][r];
#pragma unroll
            for (int kt = 1; kt < 8; ++kt) m = fmaxf(m, sv[kt][r]);
            rowm[r] = red16max(m);
        }

        float al[4], rs[4];
#pragma unroll
        for (int r = 0; r < 4; ++r) {
            const float mn = fmaxf(m_i[r], rowm[r]);
            al[r] = __expf(m_i[r] - mn);
            m_i[r] = mn;
            rs[r] = 0.f;
        }
#pragma unroll
        for (int kt = 0; kt < 8; ++kt)
#pragma unroll
            for (int r = 0; r < 4; ++r) {
                const float p = __expf(sv[kt][r] - m_i[r]);
                sv[kt][r] = p;
                rs[r] += p;
            }
#pragma unroll
        for (int r = 0; r < 4; ++r) {
            rs[r] = red16sum(rs[r]);
            l_i[r] = l_i[r] * al[r] + rs[r];
        }
#pragma unroll
        for (int nt = 0; nt < 4; ++nt)
#pragma unroll
            for (int r = 0; r < 4; ++r) o_acc[nt][r] *= al[r];

        // P -> per-wave LDS ([q][key], stride VS), fast pack
#pragma unroll
        for (int kt = 0; kt < 8; ++kt)
#pragma unroll
            for (int r = 0; r < 4; ++r)
                Pl[w * 16 * VS + (quad * 4 + r) * VS + kt * 16 + l15] = bf16fast(sv[kt][r]);

        // O += P V
#pragma unroll
        for (int kc = 0; kc < 4; ++kc) {
            short8 pf = ld8(&Pl[w * 16 * VS + l15 * VS + kc * 32 + quad * 8]);
#pragma unroll
            for (int nt = 0; nt < 4; ++nt) {
                short8 vf = ld8(&Vt[(nt * 16 + l15) * VS + kc * 32 + quad * 8]);
                o_acc[nt] = __builtin_amdgcn_mfma_f32_16x16x32_bf16(pf, vf, o_acc[nt], 0, 0, 0);
            }
        }
        __syncthreads();
    }

    // normalize + store
#pragma unroll
    for (int nt = 0; nt < 4; ++nt)
#pragma unroll
        for (int r = 0; r < 4; ++r) {
            const int row = qw + quad * 4 + r;
            const int col = h * DH + nt * 16 + l15;
            attnb[(size_t)row * DM + col] = __float2bfloat16(o_acc[nt][r] / l_i[r]);
        }
}

extern "C" void kernel_launch(void* const* d_in, const int* in_sizes, int n_in,
                              void* d_out, int out_size, void* d_ws, size_t ws_size,
                              hipStream_t stream) {
    const float* x        = (const float*)d_in[0];
    const float* w_qkv    = (const float*)d_in[1];
    const float* w_out    = (const float*)d_in[2];
    const float* rel_bias = (const float*)d_in[3];
    float* out = (float*)d_out;

    // ws layout (16-B aligned)
    char* p = (char*)d_ws;
    __hip_bfloat16* xb    = (__hip_bfloat16*)p;  p += (size_t)SEQ * DM * 2;      // 4 MB
    __hip_bfloat16* wqT   = (__hip_bfloat16*)p;  p += (size_t)3 * DM * DM * 2;   // 6 MB
    __hip_bfloat16* woT   = (__hip_bfloat16*)p;  p += (size_t)DM * DM * 2;       // 2 MB
    __hip_bfloat16* qkvb  = (__hip_bfloat16*)p;  p += (size_t)SEQ * 3 * DM * 2;  // 12 MB
    __hip_bfloat16* attnb = (__hip_bfloat16*)p;                                  // 4 MB

    // prep: weight transposes + x->bf16 (one launch)
    prep_kernel<<<dim3(160, 32), 256, 0, stream>>>(w_qkv, w_out, x, wqT, woT, xb);

    // 1) qkv = x @ w_qkv   (128x64 tiles, BK=64, 768 blocks = 3/CU)
    gemm_qkv<<<dim3(3 * DM / 64, SEQ / 128), 256, 0, stream>>>(
        xb, wqT, qkvb, SEQ, 3 * DM, DM);

    // 2) attention (V transposed in-LDS; no separate transpose kernel)
    attn_mfma<<<dim3(SEQ / 64, NH), 256, 0, stream>>>(qkvb, rel_bias, attnb);

    // 3) out = attn @ w_out  (64x64 tiles, BK=64, 512 blocks = 2/CU)
    gemm_out<<<dim3(DM / 64, SEQ / 64), 256, 0, stream>>>(
        attnb, woT, out, SEQ, DM, DM);
}

// Round 12
// 168.033 us; speedup vs baseline: 1.0190x; 1.0190x over previous
//
#include <hip/hip_runtime.h>
#include <hip/hip_bf16.h>

#define SEQ   2048
#define DM    1024
#define NH    16
#define DH    64
#define MAXD  128

#define LOG2E 1.44269504f

typedef __attribute__((ext_vector_type(8))) short  short8;   // 8 bf16 = 4 VGPRs
typedef __attribute__((ext_vector_type(4))) float  float4v;  // MFMA 16x16 accumulator

__device__ __forceinline__ short8 ld8(const void* p) {
    short8 v; __builtin_memcpy(&v, p, 16); return v;
}
__device__ __forceinline__ void st8(void* p, short8 v) {
    __builtin_memcpy(p, &v, 16);
}
__device__ __forceinline__ short bf16bits(float f) {
    __hip_bfloat16 b = __float2bfloat16(f);
    short s; __builtin_memcpy(&s, &b, 2); return s;
}
// fast bf16 pack: round-half-up (2 VALU ops). Used on P in [0,1].
__device__ __forceinline__ short bf16fast(float f) {
    unsigned u = __builtin_bit_cast(unsigned, f);
    return (short)((u + 0x8000u) >> 16);
}
__device__ __forceinline__ float bits2f(short s) {
    unsigned u = (unsigned)(unsigned short)s << 16;
    return __builtin_bit_cast(float, u);
}

// async global->LDS, 16 B per lane. lds = WAVE-UNIFORM base (HW adds lane*16).
__device__ __forceinline__ void async16(void* lds, const void* g) {
    __builtin_amdgcn_global_load_lds(
        (const __attribute__((address_space(1))) unsigned int*)g,
        (__attribute__((address_space(3))) unsigned int*)lds, 16, 0, 0);
}

// DPP cross-lane (16-lane group) reductions — VALU-latency, no LDS pipe.
template <int CTRL>
__device__ __forceinline__ float dppmov(float x) {
    return __builtin_bit_cast(float,
        __builtin_amdgcn_update_dpp(0, __builtin_bit_cast(int, x), CTRL, 0xf, 0xf, true));
}
__device__ __forceinline__ float red16max(float x) {
    x = fmaxf(x, dppmov<0xB1>(x));
    x = fmaxf(x, dppmov<0x4E>(x));
    x = fmaxf(x, dppmov<0x141>(x));
    x = fmaxf(x, dppmov<0x140>(x));
    return x;
}
__device__ __forceinline__ float red16sum(float x) {
    x += dppmov<0xB1>(x);
    x += dppmov<0x4E>(x);
    x += dppmov<0x141>(x);
    x += dppmov<0x140>(x);
    return x;
}

// ---------------------------------------------------------------------------
// Fused prep: weight transposes (fp32->bf16) + x fp32->bf16 convert.
// grid (160, 32): bx<96 wq-transpose; 96<=bx<128 wo-transpose; bx>=128 cvt.
// ---------------------------------------------------------------------------
__global__ __launch_bounds__(256) void prep_kernel(
    const float* __restrict__ wq, const float* __restrict__ wo,
    const float* __restrict__ x,
    __hip_bfloat16* __restrict__ wqT, __hip_bfloat16* __restrict__ woT,
    __hip_bfloat16* __restrict__ xb) {
    const int t = threadIdx.x;
    const int bx = blockIdx.x;
    if (bx >= 128) {
        const size_t id = (size_t)(bx - 128) * 32 + blockIdx.y;   // 0..1023
        const size_t i  = id * 2048 + t * 8;
        float f[8]; __builtin_memcpy(f, x + i, 32);
        short8 v;
#pragma unroll
        for (int j = 0; j < 8; ++j) v[j] = bf16bits(f[j]);
        st8(xb + i, v);
        return;
    }
    __shared__ __hip_bfloat16 tile[32][33];
    const int tx = t % 32, ty = t / 32;
    const int r0 = blockIdx.y * 32;
    const float* src; __hip_bfloat16* dst; int ss, ds, c0;
    if (bx < 96) { src = wq; dst = wqT; ss = 3 * DM; ds = DM; c0 = bx * 32; }
    else         { src = wo; dst = woT; ss = DM;     ds = DM; c0 = (bx - 96) * 32; }
#pragma unroll
    for (int i = 0; i < 4; ++i)
        tile[ty + i * 8][tx] = __float2bfloat16(src[(size_t)(r0 + ty + i * 8) * ss + c0 + tx]);
    __syncthreads();
#pragma unroll
    for (int i = 0; i < 4; ++i)
        dst[(size_t)(c0 + ty + i * 8) * ds + r0 + tx] = tile[tx][ty + i * 8];
}

// ---------------------------------------------------------------------------
// GEMM1: 128x64 tiles, BK=64 as two BK=32 planes. 768 blocks = 3/CU.
// Q/K-column blocks write qkvb normally; V-column blocks (col0>=2048) write
// their tile TRANSPOSED to vT via an LDS tile (coalesced 16-B stores).
// ---------------------------------------------------------------------------
__global__ __launch_bounds__(256) void gemm_qkv(
    const __hip_bfloat16* __restrict__ A,
    const __hip_bfloat16* __restrict__ BT,
    __hip_bfloat16* __restrict__ C,
    __hip_bfloat16* __restrict__ vTg,
    int M, int N, int K) {
    __shared__ short As[2 * 128 * 32];   // [kc][m][32]
    __shared__ short Bs[2 * 64 * 32];    // [kc][n][32]
    __shared__ short Tv[64 * 132];       // V-epilogue transpose tile

    const int t = threadIdx.x;
    const int w = t >> 6, lane = t & 63;
    const int l15 = lane & 15, quad = lane >> 4;
    const int row0 = blockIdx.y * 128;
    const int col0 = blockIdx.x * 64;
    const int wm = w >> 1, wn = w & 1;

    float4v acc[4][2];
#pragma unroll
    for (int i = 0; i < 4; ++i)
#pragma unroll
        for (int j = 0; j < 2; ++j) acc[i][j] = (float4v){0.f, 0.f, 0.f, 0.f};

    const int mloc0 = lane >> 2;
    const int u     = lane & 3;

    for (int k0 = 0; k0 < K; k0 += 64) {
#pragma unroll
        for (int kc = 0; kc < 2; ++kc) {
#pragma unroll
            for (int i = 0; i < 2; ++i) {
                const int c = 2 * w + i;   // A chunk 0..7
                async16(&As[kc * 4096 + c * 512],
                        A + (size_t)(row0 + c * 16 + mloc0) * K + k0 + kc * 32 + u * 8);
            }
            async16(&Bs[kc * 2048 + w * 512],
                    BT + (size_t)(col0 + w * 16 + mloc0) * K + k0 + kc * 32 + u * 8);
        }
        __syncthreads();

#pragma unroll
        for (int kc = 0; kc < 2; ++kc) {
            short8 af[4], bf[2];
#pragma unroll
            for (int mt = 0; mt < 4; ++mt)
                af[mt] = ld8(&As[kc * 4096 + (wm * 64 + mt * 16 + l15) * 32 + quad * 8]);
#pragma unroll
            for (int nt = 0; nt < 2; ++nt)
                bf[nt] = ld8(&Bs[kc * 2048 + (wn * 32 + nt * 16 + l15) * 32 + quad * 8]);
#pragma unroll
            for (int mt = 0; mt < 4; ++mt)
#pragma unroll
                for (int nt = 0; nt < 2; ++nt)
                    acc[mt][nt] = __builtin_amdgcn_mfma_f32_16x16x32_bf16(
                        af[mt], bf[nt], acc[mt][nt], 0, 0, 0);
        }
        __syncthreads();
    }

    if (col0 < 2 * DM) {
        // Q/K block: normal store
#pragma unroll
        for (int mt = 0; mt < 4; ++mt)
#pragma unroll
            for (int nt = 0; nt < 2; ++nt)
#pragma unroll
                for (int r = 0; r < 4; ++r) {
                    const int row = row0 + wm * 64 + mt * 16 + quad * 4 + r;
                    const int col = col0 + wn * 32 + nt * 16 + l15;
                    C[(size_t)row * N + col] = __float2bfloat16(acc[mt][nt][r]);
                }
    } else {
        // V block: transpose in LDS, then coalesced store to vT
#pragma unroll
        for (int mt = 0; mt < 4; ++mt)
#pragma unroll
            for (int nt = 0; nt < 2; ++nt)
#pragma unroll
                for (int r = 0; r < 4; ++r)
                    Tv[(wn * 32 + nt * 16 + l15) * 132 + wm * 64 + mt * 16 + quad * 4 + r] =
                        bf16bits(acc[mt][nt][r]);
        __syncthreads();
#pragma unroll
        for (int p = 0; p < 4; ++p) {
            const int idx = p * 256 + t;
            const int dl = idx >> 4, uu = idx & 15;
            st8(&vTg[((size_t)(col0 - 2 * DM) + dl) * SEQ + row0 + uu * 8],
                ld8(&Tv[dl * 132 + uu * 8]));
        }
    }
}

// ---------------------------------------------------------------------------
// GEMM3: 64x64 tiles, BK=64 as two BK=32 planes. fp32 out. 512 blocks = 2/CU.
// ---------------------------------------------------------------------------
__global__ __launch_bounds__(256) void gemm_out(
    const __hip_bfloat16* __restrict__ A,
    const __hip_bfloat16* __restrict__ BT,
    float* __restrict__ C,
    int M, int N, int K) {
    __shared__ short As[2 * 64 * 32];
    __shared__ short Bs[2 * 64 * 32];

    const int t = threadIdx.x;
    const int w = t >> 6, lane = t & 63;
    const int l15 = lane & 15, quad = lane >> 4;
    const int row0 = blockIdx.y * 64;
    const int col0 = blockIdx.x * 64;
    const int wm = w >> 1, wn = w & 1;

    float4v acc[2][2];
#pragma unroll
    for (int i = 0; i < 2; ++i)
#pragma unroll
        for (int j = 0; j < 2; ++j) acc[i][j] = (float4v){0.f, 0.f, 0.f, 0.f};

    const int mloc0 = lane >> 2;
    const int u     = lane & 3;

    for (int k0 = 0; k0 < K; k0 += 64) {
#pragma unroll
        for (int kc = 0; kc < 2; ++kc) {
            async16(&As[kc * 2048 + w * 512],
                    A + (size_t)(row0 + w * 16 + mloc0) * K + k0 + kc * 32 + u * 8);
            async16(&Bs[kc * 2048 + w * 512],
                    BT + (size_t)(col0 + w * 16 + mloc0) * K + k0 + kc * 32 + u * 8);
        }
        __syncthreads();

#pragma unroll
        for (int kc = 0; kc < 2; ++kc) {
            short8 af[2], bf[2];
#pragma unroll
            for (int mt = 0; mt < 2; ++mt)
                af[mt] = ld8(&As[kc * 2048 + (wm * 32 + mt * 16 + l15) * 32 + quad * 8]);
#pragma unroll
            for (int nt = 0; nt < 2; ++nt)
                bf[nt] = ld8(&Bs[kc * 2048 + (wn * 32 + nt * 16 + l15) * 32 + quad * 8]);
#pragma unroll
            for (int mt = 0; mt < 2; ++mt)
#pragma unroll
                for (int nt = 0; nt < 2; ++nt)
                    acc[mt][nt] = __builtin_amdgcn_mfma_f32_16x16x32_bf16(
                        af[mt], bf[nt], acc[mt][nt], 0, 0, 0);
        }
        __syncthreads();
    }

#pragma unroll
    for (int mt = 0; mt < 2; ++mt)
#pragma unroll
        for (int nt = 0; nt < 2; ++nt)
#pragma unroll
            for (int r = 0; r < 4; ++r) {
                const int row = row0 + wm * 32 + mt * 16 + quad * 4 + r;
                const int col = col0 + wn * 32 + nt * 16 + l15;
                C[(size_t)row * N + col] = acc[mt][nt][r];
            }
}

// ---------------------------------------------------------------------------
// MFMA flash attention (R10 fast staging), 128-key tiles, DPP softmax,
// uniform-bias fast path, exp2-domain softmax (log2e folded into Q and bias).
// ---------------------------------------------------------------------------
#define TK  128   // keys per iteration
#define KS  68    // Kt row stride (shorts), 34 dwords
#define VS  132   // Vt / Pl row stride (shorts), 66 dwords

__global__ __launch_bounds__(256) void attn_mfma(
    const __hip_bfloat16* __restrict__ qkv,
    const __hip_bfloat16* __restrict__ vT,
    const float* __restrict__ rel_bias,
    __hip_bfloat16* __restrict__ attnb) {
    __shared__ short Kt[TK * KS];        // [key][d]
    __shared__ short Vt[DH * VS];        // [d][key]
    __shared__ short Pl[4 * 16 * VS];    // per-wave P [q][key]
    __shared__ float biasL[MAXD];

    const int t = threadIdx.x;
    const int w = t >> 6, lane = t & 63;
    const int l15 = lane & 15, quad = lane >> 4;
    const int h  = blockIdx.y;
    const int q0 = blockIdx.x * 64;
    const int qw = q0 + w * 16;

    if (t < MAXD) biasL[t] = rel_bias[t * NH + h] * LOG2E;

    // persistent Q fragments, pre-scaled by 0.125*log2e (exp2 domain)
    short8 qf[2];
#pragma unroll
    for (int c = 0; c < 2; ++c) {
        short8 raw = ld8(qkv + (size_t)(qw + l15) * (3 * DM) + h * DH + c * 32 + quad * 8);
#pragma unroll
        for (int j = 0; j < 8; ++j) qf[c][j] = bf16bits(bits2f(raw[j]) * (0.125f * LOG2E));
    }

    float4v o_acc[4];
#pragma unroll
    for (int nt = 0; nt < 4; ++nt) o_acc[nt] = (float4v){0.f, 0.f, 0.f, 0.f};
    float m_i[4], l_i[4];
#pragma unroll
    for (int r = 0; r < 4; ++r) { m_i[r] = -1e30f; l_i[r] = 0.f; }

    for (int kb = 0; kb < SEQ / TK; ++kb) {
        const int k0 = kb * TK;
        // stage K [key][d] and V [d][key] (vector, from qkv and vT)
#pragma unroll
        for (int p = 0; p < 4; ++p) {
            const int idx = p * 256 + t;
            const int row = idx >> 3, u = idx & 7;
            st8(&Kt[row * KS + u * 8],
                ld8(qkv + (size_t)(k0 + row) * (3 * DM) + DM + h * DH + u * 8));
        }
#pragma unroll
        for (int p = 0; p < 4; ++p) {
            const int idx = p * 256 + t;
            const int row = idx >> 4, u = idx & 15;
            st8(&Vt[row * VS + u * 8],
                ld8(vT + (size_t)(h * DH + row) * SEQ + k0 + u * 8));
        }
        __syncthreads();

        // S = Q K^T : 8 key-blocks of 16 (exp2 domain)
        float4v s_acc[8];
#pragma unroll
        for (int kt = 0; kt < 8; ++kt) s_acc[kt] = (float4v){0.f, 0.f, 0.f, 0.f};
#pragma unroll
        for (int c = 0; c < 2; ++c)
#pragma unroll
            for (int kt = 0; kt < 8; ++kt) {
                short8 kf = ld8(&Kt[(kt * 16 + l15) * KS + (c * 4 + quad) * 8]);
                s_acc[kt] = __builtin_amdgcn_mfma_f32_16x16x32_bf16(qf[c], kf, s_acc[kt], 0, 0, 0);
            }

        // bias (wave-uniform fast path when whole tile is at max distance)
        float sv[8][4];
        const int dlo = k0 - (qw + 15);
        const int dhi = qw - (k0 + TK - 1);
        if (dlo >= MAXD - 1 || dhi >= MAXD - 1) {
            const float bu = biasL[MAXD - 1];
#pragma unroll
            for (int kt = 0; kt < 8; ++kt)
#pragma unroll
                for (int r = 0; r < 4; ++r) sv[kt][r] = s_acc[kt][r] + bu;
        } else {
#pragma unroll
            for (int kt = 0; kt < 8; ++kt)
#pragma unroll
                for (int r = 0; r < 4; ++r) {
                    const int kg = k0 + kt * 16 + l15;
                    const int qg = qw + quad * 4 + r;
                    int rel = kg - qg; if (rel < 0) rel = -rel;
                    if (rel > MAXD - 1) rel = MAXD - 1;
                    sv[kt][r] = s_acc[kt][r] + biasL[rel];
                }
        }

        // online softmax in exp2 domain (DPP reductions per quad-row)
        float rowm[4];
#pragma unroll
        for (int r = 0; r < 4; ++r) {
            float m = sv[0][r];
#pragma unroll
            for (int kt = 1; kt < 8; ++kt) m = fmaxf(m, sv[kt][r]);
            rowm[r] = red16max(m);
        }

        float al[4], rs[4];
#pragma unroll
        for (int r = 0; r < 4; ++r) {
            const float mn = fmaxf(m_i[r], rowm[r]);
            al[r] = exp2f(m_i[r] - mn);
            m_i[r] = mn;
            rs[r] = 0.f;
        }
#pragma unroll
        for (int kt = 0; kt < 8; ++kt)
#pragma unroll
            for (int r = 0; r < 4; ++r) {
                const float p = exp2f(sv[kt][r] - m_i[r]);
                sv[kt][r] = p;
                rs[r] += p;
            }
#pragma unroll
        for (int r = 0; r < 4; ++r) {
            rs[r] = red16sum(rs[r]);
            l_i[r] = l_i[r] * al[r] + rs[r];
        }
#pragma unroll
        for (int nt = 0; nt < 4; ++nt)
#pragma unroll
            for (int r = 0; r < 4; ++r) o_acc[nt][r] *= al[r];

        // P -> per-wave LDS ([q][key], stride VS), fast pack
#pragma unroll
        for (int kt = 0; kt < 8; ++kt)
#pragma unroll
            for (int r = 0; r < 4; ++r)
                Pl[w * 16 * VS + (quad * 4 + r) * VS + kt * 16 + l15] = bf16fast(sv[kt][r]);

        // O += P V
#pragma unroll
        for (int kc = 0; kc < 4; ++kc) {
            short8 pf = ld8(&Pl[w * 16 * VS + l15 * VS + kc * 32 + quad * 8]);
#pragma unroll
            for (int nt = 0; nt < 4; ++nt) {
                short8 vf = ld8(&Vt[(nt * 16 + l15) * VS + kc * 32 + quad * 8]);
                o_acc[nt] = __builtin_amdgcn_mfma_f32_16x16x32_bf16(pf, vf, o_acc[nt], 0, 0, 0);
            }
        }
        __syncthreads();
    }

    // normalize + store
#pragma unroll
    for (int nt = 0; nt < 4; ++nt)
#pragma unroll
        for (int r = 0; r < 4; ++r) {
            const int row = qw + quad * 4 + r;
            const int col = h * DH + nt * 16 + l15;
            attnb[(size_t)row * DM + col] = __float2bfloat16(o_acc[nt][r] / l_i[r]);
        }
}

extern "C" void kernel_launch(void* const* d_in, const int* in_sizes, int n_in,
                              void* d_out, int out_size, void* d_ws, size_t ws_size,
                              hipStream_t stream) {
    const float* x        = (const float*)d_in[0];
    const float* w_qkv    = (const float*)d_in[1];
    const float* w_out    = (const float*)d_in[2];
    const float* rel_bias = (const float*)d_in[3];
    float* out = (float*)d_out;

    // ws layout (16-B aligned)
    char* p = (char*)d_ws;
    __hip_bfloat16* xb    = (__hip_bfloat16*)p;  p += (size_t)SEQ * DM * 2;      // 4 MB
    __hip_bfloat16* wqT   = (__hip_bfloat16*)p;  p += (size_t)3 * DM * DM * 2;   // 6 MB
    __hip_bfloat16* woT   = (__hip_bfloat16*)p;  p += (size_t)DM * DM * 2;       // 2 MB
    __hip_bfloat16* qkvb  = (__hip_bfloat16*)p;  p += (size_t)SEQ * 3 * DM * 2;  // 12 MB
    __hip_bfloat16* vT    = (__hip_bfloat16*)p;  p += (size_t)DM * SEQ * 2;      // 4 MB
    __hip_bfloat16* attnb = (__hip_bfloat16*)p;                                  // 4 MB

    // prep: weight transposes + x->bf16 (one launch)
    prep_kernel<<<dim3(160, 32), 256, 0, stream>>>(w_qkv, w_out, x, wqT, woT, xb);

    // 1) qkv = x @ w_qkv; V-columns written transposed to vT in-epilogue
    gemm_qkv<<<dim3(3 * DM / 64, SEQ / 128), 256, 0, stream>>>(
        xb, wqT, qkvb, vT, SEQ, 3 * DM, DM);

    // 2) attention (fast vector staging from qkvb + vT)
    attn_mfma<<<dim3(SEQ / 64, NH), 256, 0, stream>>>(qkvb, vT, rel_bias, attnb);

    // 3) out = attn @ w_out  (64x64 tiles, BK=64, 512 blocks = 2/CU)
    gemm_out<<<dim3(DM / 64, SEQ / 64), 256, 0, stream>>>(
        attnb, woT, out, SEQ, DM, DM);
}

// Round 13
// 165.359 us; speedup vs baseline: 1.0355x; 1.0162x over previous
//
#include <hip/hip_runtime.h>
#include <hip/hip_bf16.h>

#define SEQ   2048
#define DM    1024
#define NH    16
#define DH    64
#define MAXD  128

#define LOG2E 1.44269504f

typedef __attribute__((ext_vector_type(8))) short  short8;   // 8 bf16 = 4 VGPRs
typedef __attribute__((ext_vector_type(4))) float  float4v;  // MFMA 16x16 accumulator

__device__ __forceinline__ short8 ld8(const void* p) {
    short8 v; __builtin_memcpy(&v, p, 16); return v;
}
__device__ __forceinline__ void st8(void* p, short8 v) {
    __builtin_memcpy(p, &v, 16);
}
__device__ __forceinline__ short bf16bits(float f) {
    __hip_bfloat16 b = __float2bfloat16(f);
    short s; __builtin_memcpy(&s, &b, 2); return s;
}
// fast bf16 pack: round-half-up (2 VALU ops). Used on P in [0,1].
__device__ __forceinline__ short bf16fast(float f) {
    unsigned u = __builtin_bit_cast(unsigned, f);
    return (short)((u + 0x8000u) >> 16);
}
__device__ __forceinline__ float bits2f(short s) {
    unsigned u = (unsigned)(unsigned short)s << 16;
    return __builtin_bit_cast(float, u);
}
// raw v_exp_f32 (2^x) — bypasses OCML's denorm fixup (results flushing to 0 is fine here)
__device__ __forceinline__ float fexp2(float x) {
    float r; asm("v_exp_f32 %0, %1" : "=v"(r) : "v"(x)); return r;
}

// async global->LDS, 16 B per lane. lds = WAVE-UNIFORM base (HW adds lane*16).
__device__ __forceinline__ void async16(void* lds, const void* g) {
    __builtin_amdgcn_global_load_lds(
        (const __attribute__((address_space(1))) unsigned int*)g,
        (__attribute__((address_space(3))) unsigned int*)lds, 16, 0, 0);
}

// DPP cross-lane (16-lane group) reductions — VALU-latency, no LDS pipe.
template <int CTRL>
__device__ __forceinline__ float dppmov(float x) {
    return __builtin_bit_cast(float,
        __builtin_amdgcn_update_dpp(0, __builtin_bit_cast(int, x), CTRL, 0xf, 0xf, true));
}
__device__ __forceinline__ float red16max(float x) {
    x = fmaxf(x, dppmov<0xB1>(x));
    x = fmaxf(x, dppmov<0x4E>(x));
    x = fmaxf(x, dppmov<0x141>(x));
    x = fmaxf(x, dppmov<0x140>(x));
    return x;
}
__device__ __forceinline__ float red16sum(float x) {
    x += dppmov<0xB1>(x);
    x += dppmov<0x4E>(x);
    x += dppmov<0x141>(x);
    x += dppmov<0x140>(x);
    return x;
}

// ---------------------------------------------------------------------------
// Fused prep: weight transposes (fp32->bf16) + x fp32->bf16 convert.
// ---------------------------------------------------------------------------
__global__ __launch_bounds__(256) void prep_kernel(
    const float* __restrict__ wq, const float* __restrict__ wo,
    const float* __restrict__ x,
    __hip_bfloat16* __restrict__ wqT, __hip_bfloat16* __restrict__ woT,
    __hip_bfloat16* __restrict__ xb) {
    const int t = threadIdx.x;
    const int bx = blockIdx.x;
    if (bx >= 128) {
        const size_t id = (size_t)(bx - 128) * 32 + blockIdx.y;
        const size_t i  = id * 2048 + t * 8;
        float f[8]; __builtin_memcpy(f, x + i, 32);
        short8 v;
#pragma unroll
        for (int j = 0; j < 8; ++j) v[j] = bf16bits(f[j]);
        st8(xb + i, v);
        return;
    }
    __shared__ __hip_bfloat16 tile[32][33];
    const int tx = t % 32, ty = t / 32;
    const int r0 = blockIdx.y * 32;
    const float* src; __hip_bfloat16* dst; int ss, ds, c0;
    if (bx < 96) { src = wq; dst = wqT; ss = 3 * DM; ds = DM; c0 = bx * 32; }
    else         { src = wo; dst = woT; ss = DM;     ds = DM; c0 = (bx - 96) * 32; }
#pragma unroll
    for (int i = 0; i < 4; ++i)
        tile[ty + i * 8][tx] = __float2bfloat16(src[(size_t)(r0 + ty + i * 8) * ss + c0 + tx]);
    __syncthreads();
#pragma unroll
    for (int i = 0; i < 4; ++i)
        dst[(size_t)(c0 + ty + i * 8) * ds + r0 + tx] = tile[tx][ty + i * 8];
}

// ---------------------------------------------------------------------------
// GEMM1: 128x64 tiles, BK=64 as two BK=32 planes. 768 blocks = 3/CU.
// V-column blocks (col0>=2048) write their tile transposed to vT.
// ---------------------------------------------------------------------------
__global__ __launch_bounds__(256) void gemm_qkv(
    const __hip_bfloat16* __restrict__ A,
    const __hip_bfloat16* __restrict__ BT,
    __hip_bfloat16* __restrict__ C,
    __hip_bfloat16* __restrict__ vTg,
    int M, int N, int K) {
    __shared__ short As[2 * 128 * 32];
    __shared__ short Bs[2 * 64 * 32];
    __shared__ short Tv[64 * 132];

    const int t = threadIdx.x;
    const int w = t >> 6, lane = t & 63;
    const int l15 = lane & 15, quad = lane >> 4;
    const int row0 = blockIdx.y * 128;
    const int col0 = blockIdx.x * 64;
    const int wm = w >> 1, wn = w & 1;

    float4v acc[4][2];
#pragma unroll
    for (int i = 0; i < 4; ++i)
#pragma unroll
        for (int j = 0; j < 2; ++j) acc[i][j] = (float4v){0.f, 0.f, 0.f, 0.f};

    const int mloc0 = lane >> 2;
    const int u     = lane & 3;

    for (int k0 = 0; k0 < K; k0 += 64) {
#pragma unroll
        for (int kc = 0; kc < 2; ++kc) {
#pragma unroll
            for (int i = 0; i < 2; ++i) {
                const int c = 2 * w + i;
                async16(&As[kc * 4096 + c * 512],
                        A + (size_t)(row0 + c * 16 + mloc0) * K + k0 + kc * 32 + u * 8);
            }
            async16(&Bs[kc * 2048 + w * 512],
                    BT + (size_t)(col0 + w * 16 + mloc0) * K + k0 + kc * 32 + u * 8);
        }
        __syncthreads();

#pragma unroll
        for (int kc = 0; kc < 2; ++kc) {
            short8 af[4], bf[2];
#pragma unroll
            for (int mt = 0; mt < 4; ++mt)
                af[mt] = ld8(&As[kc * 4096 + (wm * 64 + mt * 16 + l15) * 32 + quad * 8]);
#pragma unroll
            for (int nt = 0; nt < 2; ++nt)
                bf[nt] = ld8(&Bs[kc * 2048 + (wn * 32 + nt * 16 + l15) * 32 + quad * 8]);
#pragma unroll
            for (int mt = 0; mt < 4; ++mt)
#pragma unroll
                for (int nt = 0; nt < 2; ++nt)
                    acc[mt][nt] = __builtin_amdgcn_mfma_f32_16x16x32_bf16(
                        af[mt], bf[nt], acc[mt][nt], 0, 0, 0);
        }
        __syncthreads();
    }

    if (col0 < 2 * DM) {
#pragma unroll
        for (int mt = 0; mt < 4; ++mt)
#pragma unroll
            for (int nt = 0; nt < 2; ++nt)
#pragma unroll
                for (int r = 0; r < 4; ++r) {
                    const int row = row0 + wm * 64 + mt * 16 + quad * 4 + r;
                    const int col = col0 + wn * 32 + nt * 16 + l15;
                    C[(size_t)row * N + col] = __float2bfloat16(acc[mt][nt][r]);
                }
    } else {
#pragma unroll
        for (int mt = 0; mt < 4; ++mt)
#pragma unroll
            for (int nt = 0; nt < 2; ++nt)
#pragma unroll
                for (int r = 0; r < 4; ++r)
                    Tv[(wn * 32 + nt * 16 + l15) * 132 + wm * 64 + mt * 16 + quad * 4 + r] =
                        bf16bits(acc[mt][nt][r]);
        __syncthreads();
#pragma unroll
        for (int p = 0; p < 4; ++p) {
            const int idx = p * 256 + t;
            const int dl = idx >> 4, uu = idx & 15;
            st8(&vTg[((size_t)(col0 - 2 * DM) + dl) * SEQ + row0 + uu * 8],
                ld8(&Tv[dl * 132 + uu * 8]));
        }
    }
}

// ---------------------------------------------------------------------------
// GEMM3: 64x64 tiles, BK=64. fp32 out. 512 blocks = 2/CU.
// ---------------------------------------------------------------------------
__global__ __launch_bounds__(256) void gemm_out(
    const __hip_bfloat16* __restrict__ A,
    const __hip_bfloat16* __restrict__ BT,
    float* __restrict__ C,
    int M, int N, int K) {
    __shared__ short As[2 * 64 * 32];
    __shared__ short Bs[2 * 64 * 32];

    const int t = threadIdx.x;
    const int w = t >> 6, lane = t & 63;
    const int l15 = lane & 15, quad = lane >> 4;
    const int row0 = blockIdx.y * 64;
    const int col0 = blockIdx.x * 64;
    const int wm = w >> 1, wn = w & 1;

    float4v acc[2][2];
#pragma unroll
    for (int i = 0; i < 2; ++i)
#pragma unroll
        for (int j = 0; j < 2; ++j) acc[i][j] = (float4v){0.f, 0.f, 0.f, 0.f};

    const int mloc0 = lane >> 2;
    const int u     = lane & 3;

    for (int k0 = 0; k0 < K; k0 += 64) {
#pragma unroll
        for (int kc = 0; kc < 2; ++kc) {
            async16(&As[kc * 2048 + w * 512],
                    A + (size_t)(row0 + w * 16 + mloc0) * K + k0 + kc * 32 + u * 8);
            async16(&Bs[kc * 2048 + w * 512],
                    BT + (size_t)(col0 + w * 16 + mloc0) * K + k0 + kc * 32 + u * 8);
        }
        __syncthreads();

#pragma unroll
        for (int kc = 0; kc < 2; ++kc) {
            short8 af[2], bf[2];
#pragma unroll
            for (int mt = 0; mt < 2; ++mt)
                af[mt] = ld8(&As[kc * 2048 + (wm * 32 + mt * 16 + l15) * 32 + quad * 8]);
#pragma unroll
            for (int nt = 0; nt < 2; ++nt)
                bf[nt] = ld8(&Bs[kc * 2048 + (wn * 32 + nt * 16 + l15) * 32 + quad * 8]);
#pragma unroll
            for (int mt = 0; mt < 2; ++mt)
#pragma unroll
                for (int nt = 0; nt < 2; ++nt)
                    acc[mt][nt] = __builtin_amdgcn_mfma_f32_16x16x32_bf16(
                        af[mt], bf[nt], acc[mt][nt], 0, 0, 0);
        }
        __syncthreads();
    }

#pragma unroll
    for (int mt = 0; mt < 2; ++mt)
#pragma unroll
        for (int nt = 0; nt < 2; ++nt)
#pragma unroll
            for (int r = 0; r < 4; ++r) {
                const int row = row0 + wm * 32 + mt * 16 + quad * 4 + r;
                const int col = col0 + wn * 32 + nt * 16 + l15;
                C[(size_t)row * N + col] = acc[mt][nt][r];
            }
}

// ---------------------------------------------------------------------------
// MFMA flash attention, K-SPLIT 2: grid (32, 16, 2); block s handles keys
// s*1024 .. +1023 (8 tiles of 128). Pl ALIASED into Kt (disjoint lifetimes,
// extra mid-tile barrier) -> LDS 34.8 KB -> 4 blocks/CU, 16 waves/CU.
// Emits unnormalized partial O (bf16) + m,l (fp32, exp2 domain).
// ---------------------------------------------------------------------------
#define TK  128   // keys per tile
#define KS  68    // Kt row stride (shorts), 34 dwords
#define VS  132   // Vt / Pl row stride (shorts), 66 dwords

__global__ __launch_bounds__(256) void attn_mfma(
    const __hip_bfloat16* __restrict__ qkv,
    const __hip_bfloat16* __restrict__ vT,
    const float* __restrict__ rel_bias,
    __hip_bfloat16* __restrict__ Opart,   // [2][NH][SEQ][DH] bf16 unnormalized
    float* __restrict__ mlbuf) {          // [2][NH][SEQ][2] fp32 {m,l}
    __shared__ short KtPl[TK * KS];      // Kt [key][d]; later Pl [q][key] stride VS
    __shared__ short Vt[DH * VS];        // [d][key]
    __shared__ float biasL[MAXD];

    const int t = threadIdx.x;
    const int w = t >> 6, lane = t & 63;
    const int l15 = lane & 15, quad = lane >> 4;
    const int h  = blockIdx.y;
    const int s  = blockIdx.z;
    const int q0 = blockIdx.x * 64;
    const int qw = q0 + w * 16;

    if (t < MAXD) biasL[t] = rel_bias[t * NH + h] * LOG2E;

    // persistent Q fragments, pre-scaled by 0.125*log2e (exp2 domain)
    short8 qf[2];
#pragma unroll
    for (int c = 0; c < 2; ++c) {
        short8 raw = ld8(qkv + (size_t)(qw + l15) * (3 * DM) + h * DH + c * 32 + quad * 8);
#pragma unroll
        for (int j = 0; j < 8; ++j) qf[c][j] = bf16bits(bits2f(raw[j]) * (0.125f * LOG2E));
    }

    float4v o_acc[4];
#pragma unroll
    for (int nt = 0; nt < 4; ++nt) o_acc[nt] = (float4v){0.f, 0.f, 0.f, 0.f};
    float m_i[4], l_i[4];
#pragma unroll
    for (int r = 0; r < 4; ++r) { m_i[r] = -1e30f; l_i[r] = 0.f; }

    for (int kb = 0; kb < 8; ++kb) {
        const int k0 = s * (SEQ / 2) + kb * TK;
        // stage K [key][d] and V [d][key]
#pragma unroll
        for (int p = 0; p < 4; ++p) {
            const int idx = p * 256 + t;
            const int row = idx >> 3, u = idx & 7;
            st8(&KtPl[row * KS + u * 8],
                ld8(qkv + (size_t)(k0 + row) * (3 * DM) + DM + h * DH + u * 8));
        }
#pragma unroll
        for (int p = 0; p < 4; ++p) {
            const int idx = p * 256 + t;
            const int row = idx >> 4, u = idx & 15;
            st8(&Vt[row * VS + u * 8],
                ld8(vT + (size_t)(h * DH + row) * SEQ + k0 + u * 8));
        }
        __syncthreads();

        // S = Q K^T (exp2 domain)
        float4v s_acc[8];
#pragma unroll
        for (int kt = 0; kt < 8; ++kt) s_acc[kt] = (float4v){0.f, 0.f, 0.f, 0.f};
#pragma unroll
        for (int c = 0; c < 2; ++c)
#pragma unroll
            for (int kt = 0; kt < 8; ++kt) {
                short8 kf = ld8(&KtPl[(kt * 16 + l15) * KS + (c * 4 + quad) * 8]);
                s_acc[kt] = __builtin_amdgcn_mfma_f32_16x16x32_bf16(qf[c], kf, s_acc[kt], 0, 0, 0);
            }

        // bias
        float sv[8][4];
        const int dlo = k0 - (qw + 15);
        const int dhi = qw - (k0 + TK - 1);
        if (dlo >= MAXD - 1 || dhi >= MAXD - 1) {
            const float bu = biasL[MAXD - 1];
#pragma unroll
            for (int kt = 0; kt < 8; ++kt)
#pragma unroll
                for (int r = 0; r < 4; ++r) sv[kt][r] = s_acc[kt][r] + bu;
        } else {
#pragma unroll
            for (int kt = 0; kt < 8; ++kt)
#pragma unroll
                for (int r = 0; r < 4; ++r) {
                    const int kg = k0 + kt * 16 + l15;
                    const int qg = qw + quad * 4 + r;
                    int rel = kg - qg; if (rel < 0) rel = -rel;
                    if (rel > MAXD - 1) rel = MAXD - 1;
                    sv[kt][r] = s_acc[kt][r] + biasL[rel];
                }
        }

        // online softmax (exp2 domain, raw v_exp)
        float rowm[4];
#pragma unroll
        for (int r = 0; r < 4; ++r) {
            float m = sv[0][r];
#pragma unroll
            for (int kt = 1; kt < 8; ++kt) m = fmaxf(m, sv[kt][r]);
            rowm[r] = red16max(m);
        }

        float al[4], rs[4];
#pragma unroll
        for (int r = 0; r < 4; ++r) {
            const float mn = fmaxf(m_i[r], rowm[r]);
            al[r] = fexp2(m_i[r] - mn);
            m_i[r] = mn;
            rs[r] = 0.f;
        }
#pragma unroll
        for (int kt = 0; kt < 8; ++kt)
#pragma unroll
            for (int r = 0; r < 4; ++r) {
                const float p = fexp2(sv[kt][r] - m_i[r]);
                sv[kt][r] = p;
                rs[r] += p;
            }
#pragma unroll
        for (int r = 0; r < 4; ++r) {
            rs[r] = red16sum(rs[r]);
            l_i[r] = l_i[r] * al[r] + rs[r];
        }
#pragma unroll
        for (int nt = 0; nt < 4; ++nt)
#pragma unroll
            for (int r = 0; r < 4; ++r) o_acc[nt][r] *= al[r];

        __syncthreads();   // all waves done reading Kt before Pl overwrites it

        // P -> per-wave LDS (aliased into KtPl, stride VS)
#pragma unroll
        for (int kt = 0; kt < 8; ++kt)
#pragma unroll
            for (int r = 0; r < 4; ++r)
                KtPl[w * 16 * VS + (quad * 4 + r) * VS + kt * 16 + l15] = bf16fast(sv[kt][r]);

        // O += P V
#pragma unroll
        for (int kc = 0; kc < 4; ++kc) {
            short8 pf = ld8(&KtPl[w * 16 * VS + l15 * VS + kc * 32 + quad * 8]);
#pragma unroll
            for (int nt = 0; nt < 4; ++nt) {
                short8 vf = ld8(&Vt[(nt * 16 + l15) * VS + kc * 32 + quad * 8]);
                o_acc[nt] = __builtin_amdgcn_mfma_f32_16x16x32_bf16(pf, vf, o_acc[nt], 0, 0, 0);
            }
        }
        __syncthreads();
    }

    // store unnormalized partial + m,l
    const size_t pb = ((size_t)s * NH + h) * SEQ;
#pragma unroll
    for (int nt = 0; nt < 4; ++nt)
#pragma unroll
        for (int r = 0; r < 4; ++r) {
            const int row = qw + quad * 4 + r;
            Opart[(pb + row) * DH + nt * 16 + l15] = __float2bfloat16(o_acc[nt][r]);
        }
    if (l15 == 0) {
#pragma unroll
        for (int r = 0; r < 4; ++r) {
            const int row = qw + quad * 4 + r;
            mlbuf[(pb + row) * 2 + 0] = m_i[r];
            mlbuf[(pb + row) * 2 + 1] = l_i[r];
        }
    }
}

// ---------------------------------------------------------------------------
// Combine the two K-split partials -> attnb. grid (32, 16), 256 threads.
// ---------------------------------------------------------------------------
__global__ __launch_bounds__(256) void attn_combine(
    const __hip_bfloat16* __restrict__ Opart,
    const float* __restrict__ mlbuf,
    __hip_bfloat16* __restrict__ attnb) {
    const int t = threadIdx.x;
    const int h = blockIdx.y;
    const int row = blockIdx.x * 64 + (t >> 2);
    const int dp  = (t & 3) * 16;

    const size_t b0 = ((size_t)0 * NH + h) * SEQ + row;
    const size_t b1 = ((size_t)1 * NH + h) * SEQ + row;
    const float m0 = mlbuf[b0 * 2], l0 = mlbuf[b0 * 2 + 1];
    const float m1 = mlbuf[b1 * 2], l1 = mlbuf[b1 * 2 + 1];
    const float M  = fmaxf(m0, m1);
    const float w0 = fexp2(m0 - M), w1 = fexp2(m1 - M);
    const float inv = 1.0f / (l0 * w0 + l1 * w1);

    short8 out[2];
#pragma unroll
    for (int half = 0; half < 2; ++half) {
        short8 a = ld8(Opart + b0 * DH + dp + half * 8);
        short8 b = ld8(Opart + b1 * DH + dp + half * 8);
#pragma unroll
        for (int j = 0; j < 8; ++j)
            out[half][j] = bf16bits((bits2f(a[j]) * w0 + bits2f(b[j]) * w1) * inv);
    }
    st8(attnb + (size_t)row * DM + h * DH + dp, out[0]);
    st8(attnb + (size_t)row * DM + h * DH + dp + 8, out[1]);
}

extern "C" void kernel_launch(void* const* d_in, const int* in_sizes, int n_in,
                              void* d_out, int out_size, void* d_ws, size_t ws_size,
                              hipStream_t stream) {
    const float* x        = (const float*)d_in[0];
    const float* w_qkv    = (const float*)d_in[1];
    const float* w_out    = (const float*)d_in[2];
    const float* rel_bias = (const float*)d_in[3];
    float* out = (float*)d_out;

    // ws layout (16-B aligned), 32 MiB total
    char* p = (char*)d_ws;
    __hip_bfloat16* xb    = (__hip_bfloat16*)p;  p += (size_t)SEQ * DM * 2;      // 4 MiB
    __hip_bfloat16* wqT   = (__hip_bfloat16*)p;  p += (size_t)3 * DM * DM * 2;   // 6 MiB
    __hip_bfloat16* woT   = (__hip_bfloat16*)p;  p += (size_t)DM * DM * 2;       // 2 MiB
    __hip_bfloat16* qkvb  = (__hip_bfloat16*)p;  p += (size_t)SEQ * 3 * DM * 2;  // 12 MiB
    __hip_bfloat16* vT    = (__hip_bfloat16*)p;  p += (size_t)DM * SEQ * 2;      // 4 MiB
    __hip_bfloat16* attnb = (__hip_bfloat16*)p;                                  // 4 MiB

    // partial buffers alias xb+wqT (dead after gemm_qkv): Opart 8 MiB, mlbuf 1 MiB
    __hip_bfloat16* Opart = (__hip_bfloat16*)d_ws;
    float*          mlbuf = (float*)((char*)d_ws + ((size_t)8 << 20));

    prep_kernel<<<dim3(160, 32), 256, 0, stream>>>(w_qkv, w_out, x, wqT, woT, xb);

    // 1) qkv = x @ w_qkv; V-columns written transposed to vT in-epilogue
    gemm_qkv<<<dim3(3 * DM / 64, SEQ / 128), 256, 0, stream>>>(
        xb, wqT, qkvb, vT, SEQ, 3 * DM, DM);

    // 2a) attention partials (K-split 2; clobbers xb/wqT via Opart/mlbuf)
    attn_mfma<<<dim3(SEQ / 64, NH, 2), 256, 0, stream>>>(
        qkvb, vT, rel_bias, Opart, mlbuf);

    // 2b) combine partials -> attnb
    attn_combine<<<dim3(SEQ / 64, NH), 256, 0, stream>>>(Opart, mlbuf, attnb);

    // 3) out = attn @ w_out
    gemm_out<<<dim3(DM / 64, SEQ / 64), 256, 0, stream>>>(
        attnb, woT, out, SEQ, DM, DM);
}

// Round 14
// 158.280 us; speedup vs baseline: 1.0818x; 1.0447x over previous
//
#include <hip/hip_runtime.h>
#include <hip/hip_bf16.h>

#define SEQ   2048
#define DM    1024
#define NH    16
#define DH    64
#define MAXD  128

#define LOG2E 1.44269504f

typedef __attribute__((ext_vector_type(8))) short  short8;   // 8 bf16 = 4 VGPRs
typedef __attribute__((ext_vector_type(4))) float  float4v;  // MFMA 16x16 accumulator

__device__ __forceinline__ short8 ld8(const void* p) {
    short8 v; __builtin_memcpy(&v, p, 16); return v;
}
__device__ __forceinline__ void st8(void* p, short8 v) {
    __builtin_memcpy(p, &v, 16);
}
__device__ __forceinline__ short bf16bits(float f) {
    __hip_bfloat16 b = __float2bfloat16(f);
    short s; __builtin_memcpy(&s, &b, 2); return s;
}
// fast bf16 pack: round-half-up (2 VALU ops). Used on P in [0,1].
__device__ __forceinline__ short bf16fast(float f) {
    unsigned u = __builtin_bit_cast(unsigned, f);
    return (short)((u + 0x8000u) >> 16);
}
__device__ __forceinline__ float bits2f(short s) {
    unsigned u = (unsigned)(unsigned short)s << 16;
    return __builtin_bit_cast(float, u);
}
// raw v_exp_f32 (2^x) — bypasses OCML denorm fixup (flush-to-zero is fine here)
__device__ __forceinline__ float fexp2(float x) {
    float r; asm("v_exp_f32 %0, %1" : "=v"(r) : "v"(x)); return r;
}

// async global->LDS, 16 B per lane. lds = WAVE-UNIFORM base (HW adds lane*16).
__device__ __forceinline__ void async16(void* lds, const void* g) {
    __builtin_amdgcn_global_load_lds(
        (const __attribute__((address_space(1))) unsigned int*)g,
        (__attribute__((address_space(3))) unsigned int*)lds, 16, 0, 0);
}

// DPP cross-lane (16-lane group) reductions — VALU-latency, no LDS pipe.
template <int CTRL>
__device__ __forceinline__ float dppmov(float x) {
    return __builtin_bit_cast(float,
        __builtin_amdgcn_update_dpp(0, __builtin_bit_cast(int, x), CTRL, 0xf, 0xf, true));
}
__device__ __forceinline__ float red16max(float x) {
    x = fmaxf(x, dppmov<0xB1>(x));
    x = fmaxf(x, dppmov<0x4E>(x));
    x = fmaxf(x, dppmov<0x141>(x));
    x = fmaxf(x, dppmov<0x140>(x));
    return x;
}
__device__ __forceinline__ float red16sum(float x) {
    x += dppmov<0xB1>(x);
    x += dppmov<0x4E>(x);
    x += dppmov<0x141>(x);
    x += dppmov<0x140>(x);
    return x;
}

// ---------------------------------------------------------------------------
// Fused prep: weight transposes (fp32->bf16) + x fp32->bf16 convert.
// ---------------------------------------------------------------------------
__global__ __launch_bounds__(256) void prep_kernel(
    const float* __restrict__ wq, const float* __restrict__ wo,
    const float* __restrict__ x,
    __hip_bfloat16* __restrict__ wqT, __hip_bfloat16* __restrict__ woT,
    __hip_bfloat16* __restrict__ xb) {
    const int t = threadIdx.x;
    const int bx = blockIdx.x;
    if (bx >= 128) {
        const size_t id = (size_t)(bx - 128) * 32 + blockIdx.y;
        const size_t i  = id * 2048 + t * 8;
        float f[8]; __builtin_memcpy(f, x + i, 32);
        short8 v;
#pragma unroll
        for (int j = 0; j < 8; ++j) v[j] = bf16bits(f[j]);
        st8(xb + i, v);
        return;
    }
    __shared__ __hip_bfloat16 tile[32][33];
    const int tx = t % 32, ty = t / 32;
    const int r0 = blockIdx.y * 32;
    const float* src; __hip_bfloat16* dst; int ss, ds, c0;
    if (bx < 96) { src = wq; dst = wqT; ss = 3 * DM; ds = DM; c0 = bx * 32; }
    else         { src = wo; dst = woT; ss = DM;     ds = DM; c0 = (bx - 96) * 32; }
#pragma unroll
    for (int i = 0; i < 4; ++i)
        tile[ty + i * 8][tx] = __float2bfloat16(src[(size_t)(r0 + ty + i * 8) * ss + c0 + tx]);
    __syncthreads();
#pragma unroll
    for (int i = 0; i < 4; ++i)
        dst[(size_t)(c0 + ty + i * 8) * ds + r0 + tx] = tile[tx][ty + i * 8];
}

// ---------------------------------------------------------------------------
// GEMM1: 128x64 tiles, BK=64 as two BK=32 planes. 768 blocks = 3/CU.
// V-column blocks (col0>=2048) write their tile transposed to vT.
// ---------------------------------------------------------------------------
__global__ __launch_bounds__(256) void gemm_qkv(
    const __hip_bfloat16* __restrict__ A,
    const __hip_bfloat16* __restrict__ BT,
    __hip_bfloat16* __restrict__ C,
    __hip_bfloat16* __restrict__ vTg,
    int M, int N, int K) {
    __shared__ short As[2 * 128 * 32];
    __shared__ short Bs[2 * 64 * 32];
    __shared__ short Tv[64 * 132];

    const int t = threadIdx.x;
    const int w = t >> 6, lane = t & 63;
    const int l15 = lane & 15, quad = lane >> 4;
    const int row0 = blockIdx.y * 128;
    const int col0 = blockIdx.x * 64;
    const int wm = w >> 1, wn = w & 1;

    float4v acc[4][2];
#pragma unroll
    for (int i = 0; i < 4; ++i)
#pragma unroll
        for (int j = 0; j < 2; ++j) acc[i][j] = (float4v){0.f, 0.f, 0.f, 0.f};

    const int mloc0 = lane >> 2;
    const int u     = lane & 3;

    for (int k0 = 0; k0 < K; k0 += 64) {
#pragma unroll
        for (int kc = 0; kc < 2; ++kc) {
#pragma unroll
            for (int i = 0; i < 2; ++i) {
                const int c = 2 * w + i;
                async16(&As[kc * 4096 + c * 512],
                        A + (size_t)(row0 + c * 16 + mloc0) * K + k0 + kc * 32 + u * 8);
            }
            async16(&Bs[kc * 2048 + w * 512],
                    BT + (size_t)(col0 + w * 16 + mloc0) * K + k0 + kc * 32 + u * 8);
        }
        __syncthreads();

#pragma unroll
        for (int kc = 0; kc < 2; ++kc) {
            short8 af[4], bf[2];
#pragma unroll
            for (int mt = 0; mt < 4; ++mt)
                af[mt] = ld8(&As[kc * 4096 + (wm * 64 + mt * 16 + l15) * 32 + quad * 8]);
#pragma unroll
            for (int nt = 0; nt < 2; ++nt)
                bf[nt] = ld8(&Bs[kc * 2048 + (wn * 32 + nt * 16 + l15) * 32 + quad * 8]);
#pragma unroll
            for (int mt = 0; mt < 4; ++mt)
#pragma unroll
                for (int nt = 0; nt < 2; ++nt)
                    acc[mt][nt] = __builtin_amdgcn_mfma_f32_16x16x32_bf16(
                        af[mt], bf[nt], acc[mt][nt], 0, 0, 0);
        }
        __syncthreads();
    }

    if (col0 < 2 * DM) {
#pragma unroll
        for (int mt = 0; mt < 4; ++mt)
#pragma unroll
            for (int nt = 0; nt < 2; ++nt)
#pragma unroll
                for (int r = 0; r < 4; ++r) {
                    const int row = row0 + wm * 64 + mt * 16 + quad * 4 + r;
                    const int col = col0 + wn * 32 + nt * 16 + l15;
                    C[(size_t)row * N + col] = __float2bfloat16(acc[mt][nt][r]);
                }
    } else {
#pragma unroll
        for (int mt = 0; mt < 4; ++mt)
#pragma unroll
            for (int nt = 0; nt < 2; ++nt)
#pragma unroll
                for (int r = 0; r < 4; ++r)
                    Tv[(wn * 32 + nt * 16 + l15) * 132 + wm * 64 + mt * 16 + quad * 4 + r] =
                        bf16bits(acc[mt][nt][r]);
        __syncthreads();
#pragma unroll
        for (int p = 0; p < 4; ++p) {
            const int idx = p * 256 + t;
            const int dl = idx >> 4, uu = idx & 15;
            st8(&vTg[((size_t)(col0 - 2 * DM) + dl) * SEQ + row0 + uu * 8],
                ld8(&Tv[dl * 132 + uu * 8]));
        }
    }
}

// ---------------------------------------------------------------------------
// GEMM3: 64x64 tiles, BK=64. fp32 out. 512 blocks = 2/CU.
// ---------------------------------------------------------------------------
__global__ __launch_bounds__(256) void gemm_out(
    const __hip_bfloat16* __restrict__ A,
    const __hip_bfloat16* __restrict__ BT,
    float* __restrict__ C,
    int M, int N, int K) {
    __shared__ short As[2 * 64 * 32];
    __shared__ short Bs[2 * 64 * 32];

    const int t = threadIdx.x;
    const int w = t >> 6, lane = t & 63;
    const int l15 = lane & 15, quad = lane >> 4;
    const int row0 = blockIdx.y * 64;
    const int col0 = blockIdx.x * 64;
    const int wm = w >> 1, wn = w & 1;

    float4v acc[2][2];
#pragma unroll
    for (int i = 0; i < 2; ++i)
#pragma unroll
        for (int j = 0; j < 2; ++j) acc[i][j] = (float4v){0.f, 0.f, 0.f, 0.f};

    const int mloc0 = lane >> 2;
    const int u     = lane & 3;

    for (int k0 = 0; k0 < K; k0 += 64) {
#pragma unroll
        for (int kc = 0; kc < 2; ++kc) {
            async16(&As[kc * 2048 + w * 512],
                    A + (size_t)(row0 + w * 16 + mloc0) * K + k0 + kc * 32 + u * 8);
            async16(&Bs[kc * 2048 + w * 512],
                    BT + (size_t)(col0 + w * 16 + mloc0) * K + k0 + kc * 32 + u * 8);
        }
        __syncthreads();

#pragma unroll
        for (int kc = 0; kc < 2; ++kc) {
            short8 af[2], bf[2];
#pragma unroll
            for (int mt = 0; mt < 2; ++mt)
                af[mt] = ld8(&As[kc * 2048 + (wm * 32 + mt * 16 + l15) * 32 + quad * 8]);
#pragma unroll
            for (int nt = 0; nt < 2; ++nt)
                bf[nt] = ld8(&Bs[kc * 2048 + (wn * 32 + nt * 16 + l15) * 32 + quad * 8]);
#pragma unroll
            for (int mt = 0; mt < 2; ++mt)
#pragma unroll
                for (int nt = 0; nt < 2; ++nt)
                    acc[mt][nt] = __builtin_amdgcn_mfma_f32_16x16x32_bf16(
                        af[mt], bf[nt], acc[mt][nt], 0, 0, 0);
        }
        __syncthreads();
    }

#pragma unroll
    for (int mt = 0; mt < 2; ++mt)
#pragma unroll
        for (int nt = 0; nt < 2; ++nt)
#pragma unroll
            for (int r = 0; r < 4; ++r) {
                const int row = row0 + wm * 32 + mt * 16 + quad * 4 + r;
                const int col = col0 + wn * 32 + nt * 16 + l15;
                C[(size_t)row * N + col] = acc[mt][nt][r];
            }
}

// ---------------------------------------------------------------------------
// MFMA flash attention: TK=128, no K-split, Pl aliased into Kt, raw v_exp,
// XCD-aware block swizzle (head h -> XCD h%8 for K/V L2 locality).
// grid = 512 1D blocks; decode: xcd=id&7, qb=(id>>3)&31, h=(id&7)+8*(id>>8).
// ---------------------------------------------------------------------------
#define TK  128   // keys per tile
#define KS  68    // Kt row stride (shorts), 34 dwords
#define VS  132   // Vt / Pl row stride (shorts), 66 dwords

__global__ __launch_bounds__(256) void attn_mfma(
    const __hip_bfloat16* __restrict__ qkv,
    const __hip_bfloat16* __restrict__ vT,
    const float* __restrict__ rel_bias,
    __hip_bfloat16* __restrict__ attnb) {
    __shared__ short KtPl[TK * KS];      // Kt [key][d]; later Pl [q][key] stride VS
    __shared__ short Vt[DH * VS];        // [d][key]
    __shared__ float biasL[MAXD];

    const int t = threadIdx.x;
    const int w = t >> 6, lane = t & 63;
    const int l15 = lane & 15, quad = lane >> 4;

    const int id = blockIdx.x;           // XCD swizzle: id%8 = XCD (round-robin)
    const int qb = (id >> 3) & 31;
    const int h  = (id & 7) + 8 * (id >> 8);
    const int q0 = qb * 64;
    const int qw = q0 + w * 16;

    if (t < MAXD) biasL[t] = rel_bias[t * NH + h] * LOG2E;

    // persistent Q fragments, pre-scaled by 0.125*log2e (exp2 domain)
    short8 qf[2];
#pragma unroll
    for (int c = 0; c < 2; ++c) {
        short8 raw = ld8(qkv + (size_t)(qw + l15) * (3 * DM) + h * DH + c * 32 + quad * 8);
#pragma unroll
        for (int j = 0; j < 8; ++j) qf[c][j] = bf16bits(bits2f(raw[j]) * (0.125f * LOG2E));
    }

    float4v o_acc[4];
#pragma unroll
    for (int nt = 0; nt < 4; ++nt) o_acc[nt] = (float4v){0.f, 0.f, 0.f, 0.f};
    float m_i[4], l_i[4];
#pragma unroll
    for (int r = 0; r < 4; ++r) { m_i[r] = -1e30f; l_i[r] = 0.f; }

    for (int kb = 0; kb < SEQ / TK; ++kb) {
        const int k0 = kb * TK;
        // stage K [key][d] and V [d][key]
#pragma unroll
        for (int p = 0; p < 4; ++p) {
            const int idx = p * 256 + t;
            const int row = idx >> 3, u = idx & 7;
            st8(&KtPl[row * KS + u * 8],
                ld8(qkv + (size_t)(k0 + row) * (3 * DM) + DM + h * DH + u * 8));
        }
#pragma unroll
        for (int p = 0; p < 4; ++p) {
            const int idx = p * 256 + t;
            const int row = idx >> 4, u = idx & 15;
            st8(&Vt[row * VS + u * 8],
                ld8(vT + (size_t)(h * DH + row) * SEQ + k0 + u * 8));
        }
        __syncthreads();

        // S = Q K^T (exp2 domain)
        float4v s_acc[8];
#pragma unroll
        for (int kt = 0; kt < 8; ++kt) s_acc[kt] = (float4v){0.f, 0.f, 0.f, 0.f};
#pragma unroll
        for (int c = 0; c < 2; ++c)
#pragma unroll
            for (int kt = 0; kt < 8; ++kt) {
                short8 kf = ld8(&KtPl[(kt * 16 + l15) * KS + (c * 4 + quad) * 8]);
                s_acc[kt] = __builtin_amdgcn_mfma_f32_16x16x32_bf16(qf[c], kf, s_acc[kt], 0, 0, 0);
            }

        // bias (wave-uniform fast path at max distance)
        float sv[8][4];
        const int dlo = k0 - (qw + 15);
        const int dhi = qw - (k0 + TK - 1);
        if (dlo >= MAXD - 1 || dhi >= MAXD - 1) {
            const float bu = biasL[MAXD - 1];
#pragma unroll
            for (int kt = 0; kt < 8; ++kt)
#pragma unroll
                for (int r = 0; r < 4; ++r) sv[kt][r] = s_acc[kt][r] + bu;
        } else {
#pragma unroll
            for (int kt = 0; kt < 8; ++kt)
#pragma unroll
                for (int r = 0; r < 4; ++r) {
                    const int kg = k0 + kt * 16 + l15;
                    const int qg = qw + quad * 4 + r;
                    int rel = kg - qg; if (rel < 0) rel = -rel;
                    if (rel > MAXD - 1) rel = MAXD - 1;
                    sv[kt][r] = s_acc[kt][r] + biasL[rel];
                }
        }

        // online softmax (exp2 domain, raw v_exp, DPP reductions)
        float rowm[4];
#pragma unroll
        for (int r = 0; r < 4; ++r) {
            float m = sv[0][r];
#pragma unroll
            for (int kt = 1; kt < 8; ++kt) m = fmaxf(m, sv[kt][r]);
            rowm[r] = red16max(m);
        }

        float al[4], rs[4];
#pragma unroll
        for (int r = 0; r < 4; ++r) {
            const float mn = fmaxf(m_i[r], rowm[r]);
            al[r] = fexp2(m_i[r] - mn);
            m_i[r] = mn;
            rs[r] = 0.f;
        }
#pragma unroll
        for (int kt = 0; kt < 8; ++kt)
#pragma unroll
            for (int r = 0; r < 4; ++r) {
                const float p = fexp2(sv[kt][r] - m_i[r]);
                sv[kt][r] = p;
                rs[r] += p;
            }
#pragma unroll
        for (int r = 0; r < 4; ++r) {
            rs[r] = red16sum(rs[r]);
            l_i[r] = l_i[r] * al[r] + rs[r];
        }
#pragma unroll
        for (int nt = 0; nt < 4; ++nt)
#pragma unroll
            for (int r = 0; r < 4; ++r) o_acc[nt][r] *= al[r];

        __syncthreads();   // all waves done reading Kt before Pl overwrites it

        // P -> per-wave LDS (aliased into KtPl, stride VS), fast pack
#pragma unroll
        for (int kt = 0; kt < 8; ++kt)
#pragma unroll
            for (int r = 0; r < 4; ++r)
                KtPl[w * 16 * VS + (quad * 4 + r) * VS + kt * 16 + l15] = bf16fast(sv[kt][r]);

        // O += P V
#pragma unroll
        for (int kc = 0; kc < 4; ++kc) {
            short8 pf = ld8(&KtPl[w * 16 * VS + l15 * VS + kc * 32 + quad * 8]);
#pragma unroll
            for (int nt = 0; nt < 4; ++nt) {
                short8 vf = ld8(&Vt[(nt * 16 + l15) * VS + kc * 32 + quad * 8]);
                o_acc[nt] = __builtin_amdgcn_mfma_f32_16x16x32_bf16(pf, vf, o_acc[nt], 0, 0, 0);
            }
        }
        __syncthreads();
    }

    // normalize + store
#pragma unroll
    for (int nt = 0; nt < 4; ++nt)
#pragma unroll
        for (int r = 0; r < 4; ++r) {
            const int row = qw + quad * 4 + r;
            const int col = h * DH + nt * 16 + l15;
            attnb[(size_t)row * DM + col] = __float2bfloat16(o_acc[nt][r] / l_i[r]);
        }
}

extern "C" void kernel_launch(void* const* d_in, const int* in_sizes, int n_in,
                              void* d_out, int out_size, void* d_ws, size_t ws_size,
                              hipStream_t stream) {
    const float* x        = (const float*)d_in[0];
    const float* w_qkv    = (const float*)d_in[1];
    const float* w_out    = (const float*)d_in[2];
    const float* rel_bias = (const float*)d_in[3];
    float* out = (float*)d_out;

    // ws layout (16-B aligned), 32 MiB total
    char* p = (char*)d_ws;
    __hip_bfloat16* xb    = (__hip_bfloat16*)p;  p += (size_t)SEQ * DM * 2;      // 4 MiB
    __hip_bfloat16* wqT   = (__hip_bfloat16*)p;  p += (size_t)3 * DM * DM * 2;   // 6 MiB
    __hip_bfloat16* woT   = (__hip_bfloat16*)p;  p += (size_t)DM * DM * 2;       // 2 MiB
    __hip_bfloat16* qkvb  = (__hip_bfloat16*)p;  p += (size_t)SEQ * 3 * DM * 2;  // 12 MiB
    __hip_bfloat16* vT    = (__hip_bfloat16*)p;  p += (size_t)DM * SEQ * 2;      // 4 MiB
    __hip_bfloat16* attnb = (__hip_bfloat16*)p;                                  // 4 MiB

    prep_kernel<<<dim3(160, 32), 256, 0, stream>>>(w_qkv, w_out, x, wqT, woT, xb);

    // 1) qkv = x @ w_qkv; V-columns written transposed to vT in-epilogue
    gemm_qkv<<<dim3(3 * DM / 64, SEQ / 128), 256, 0, stream>>>(
        xb, wqT, qkvb, vT, SEQ, 3 * DM, DM);

    // 2) attention (single kernel, XCD-swizzled 1D grid)
    attn_mfma<<<512, 256, 0, stream>>>(qkvb, vT, rel_bias, attnb);

    // 3) out = attn @ w_out
    gemm_out<<<dim3(DM / 64, SEQ / 64), 256, 0, stream>>>(
        attnb, woT, out, SEQ, DM, DM);
}